// Round 9
// baseline (677.167 us; speedup 1.0000x reference)
//
#include <hip/hip_runtime.h>
#include <math.h>

#define B_ 256
#define E_ 128
#define N_ 128
#define T_ 20
#define D_ 128
#define M_ (B_*E_)   // 32768 sequences

typedef __attribute__((ext_vector_type(8))) short bf16x8;
typedef __attribute__((ext_vector_type(4))) short s16x4;
typedef __attribute__((ext_vector_type(4))) float f32x4;
typedef __attribute__((ext_vector_type(4))) unsigned u32x4;

__device__ __forceinline__ float sigm(float x) { return 1.0f / (1.0f + __expf(-x)); }
__device__ __forceinline__ float fast_tanh(float x) {
    float e = __expf(2.f * x);
    return 1.f - 2.f / (e + 1.f);
}
__device__ __forceinline__ short f2bf(float f) {   // RNE float->bf16 (scalar)
    unsigned u = __builtin_bit_cast(unsigned, f);
    u += 0x7fffu + ((u >> 16) & 1u);
    return (short)(u >> 16);
}
// HW packed convert: 2 f32 -> 2 bf16 in one instruction (RNE).
__device__ __forceinline__ unsigned cvtpk(float lo, float hi) {
    unsigned r;
    asm("v_cvt_pk_bf16_f32 %0, %1, %2" : "=v"(r) : "v"(lo), "v"(hi));
    return r;
}
__device__ __forceinline__ bf16x8 pk8(float4 a, float4 b) {
    u32x4 u = { cvtpk(a.x,a.y), cvtpk(a.z,a.w), cvtpk(b.x,b.y), cvtpk(b.z,b.w) };
    return __builtin_bit_cast(bf16x8, u);
}
__device__ __forceinline__ bf16x8 cvt8(const float* __restrict__ p) {
    float4 u = *(const float4*)p;
    float4 v = *(const float4*)(p + 4);
    return pk8(u, v);
}

// [rows][32k] bf16 slice, 64 B/row; chunk-XOR swizzle (k2/k3 kernels).
#define SLADDR(row, chunk) ((row) * 64 + ((((chunk) ^ ((row) >> 1)) & 3) << 4))

// [rows][128 cols bf16] tile, 256 B/row, byte-XOR swizzle (k1).
__device__ __forceinline__ bf16x8 t_frag(const char* base, int row, int cb) {
    return *(const bf16x8*)(base + row * 256 + (cb ^ ((row & 7) << 4)));
}

// LDS-only barrier: drain LDS ops, sync, but DON'T drain vmcnt.
__device__ __forceinline__ void lds_barrier() {
    asm volatile("s_waitcnt lgkmcnt(0)" ::: "memory");
    __builtin_amdgcn_s_barrier();
    asm volatile("" ::: "memory");
}

// ---------------------------------------------------------------------------
// K0w: repack GRU weights (f32, row-major) into FRAGMENT-MAJOR bf16.
// Frag id = ((s*3+g)*8+dt)*4+kt  (s: 0=w_ih 1=w_hh; g: r/z/n; dt: d-tile; kt).
// Frag block = 64 lanes x 16 B contiguous (1 KB) -> k1's streamed loads are
// perfectly coalesced global_load_dwordx4, L2-resident (196 KB total).
// Lane l holds W[g*128+dt*16+(l&15)][kt*32+(l>>4)*8 .. +7] as 8 bf16.
// ---------------------------------------------------------------------------
__global__ __launch_bounds__(512) void k0w_pack(
    const float* __restrict__ wih, const float* __restrict__ whh,
    short* __restrict__ wfrag)     // [192*64*8] bf16
{
    int ft   = blockIdx.x * 512 + threadIdx.x;   // 0 .. 192*64-1
    int lane = ft & 63;
    int frag = ft >> 6;
    int kt = frag & 3;
    int dt = (frag >> 2) & 7;
    int sg = frag >> 5;           // s*3+g, 0..5
    int s  = sg / 3;
    int g  = sg % 3;
    const float* W = s ? whh : wih;
    int row = g * 128 + dt * 16 + (lane & 15);
    int k0  = kt * 32 + (lane >> 4) * 8;
    bf16x8 f = cvt8(W + (size_t)row * 128 + k0);
    *(bf16x8*)(wfrag + (size_t)ft * 8) = f;
}

// ---------------------------------------------------------------------------
// K1: persistent MFMA micro-GRU, register-lean for 2 blocks/CU.
// 512 threads (8 waves), 64 contiguous seqs/block, grid 512 -> 2 blocks/CU
// resident (16 waves/CU, 4/SIMD). Weight fragments are STREAMED from the
// frag-major L2-resident buffer (3 frags live + 3 prefetch = 24 VGPR) instead
// of pinned (96 VGPR). acc 64 + hm 16 + Xpref 8 + lens packed 4 -> ~128 regs.
// X/H tiles [64][128] bf16 XOR-swizzled, double-buffered, one LDS-only
// barrier per step. Accumulators bias-initialized.
// ---------------------------------------------------------------------------
__global__ __launch_bounds__(512, 4) void k1_gru_mfma(
    const float* __restrict__ xa, const int* __restrict__ len,
    const short* __restrict__ wfrag,
    const float* __restrict__ bih, const float* __restrict__ bhh,
    short* __restrict__ mh)        // bf16 [M][128]
{
    __shared__ __align__(16) char Xb0[64 * 256];
    __shared__ __align__(16) char Xb1[64 * 256];
    __shared__ __align__(16) char Hb0[64 * 256];
    __shared__ __align__(16) char Hb1[64 * 256];

    const int tid = threadIdx.x;
    const int l   = tid & 63;
    const int w   = tid >> 6;     // wave id 0..7 = d-tile
    const int l15 = l & 15;
    const int l4  = l >> 4;
    const int m0  = blockIdx.x * 64;

    // streamed-weight lane base: + (s*3+g)*32768 + kt*1024 selects the frag
    const char* wbase = (const char*)wfrag + w * 4096 + l * 16;
#define LDW(s, g, kt) (*(const bf16x8*)(wbase + ((s)*3+(g)) * 32768 + (kt) * 1024))

    const int dcol = w * 16 + l15;
    const float brz = bih[dcol]       + bhh[dcol];
    const float bzz = bih[128 + dcol] + bhh[128 + dcol];
    const float bin_= bih[256 + dcol];
    const float bhn_= bhh[256 + dcol];

    // lens packed 4/reg (values <= 20 fit a byte)
    unsigned lp[4];
#pragma unroll
    for (int mt = 0; mt < 4; ++mt) {
        unsigned v = 0;
#pragma unroll
        for (int r = 0; r < 4; ++r)
            v |= ((unsigned)len[m0 + mt * 16 + l4 * 4 + r] & 0xff) << (8 * r);
        lp[mt] = v;
    }

    float hm[4][4];
#pragma unroll
    for (int mt = 0; mt < 4; ++mt)
#pragma unroll
        for (int r = 0; r < 4; ++r) hm[mt][r] = 0.f;

    // ---- X staging map: thread handles rows sr0, sr0+32; 8 cols at sc8 ----
    const int sr0 = tid >> 4;          // 0..31
    const int sc8 = (tid & 15) * 8;    // col in elems
    const int lbA = sr0 * 256 + ((sc8 * 2) ^ ((sr0 & 7) << 4));
    const int lbB = (sr0 + 32) * 256 + ((sc8 * 2) ^ (((sr0 + 32) & 7) << 4));
    const float* xbA = xa + (size_t)(m0 + sr0     ) * (T_ * D_) + sc8;
    const float* xbB = xa + (size_t)(m0 + sr0 + 32) * (T_ * D_) + sc8;

    // prologue: stage X_0; issue prefetch of X_1
    {
        const float4* pA = (const float4*)xbA;
        const float4* pB = (const float4*)xbB;
        *(bf16x8*)(Xb0 + lbA) = pk8(pA[0], pA[1]);
        *(bf16x8*)(Xb0 + lbB) = pk8(pB[0], pB[1]);
    }
    float4 xp0, xp1, xq0, xq1;
    {
        const float4* qA = (const float4*)(xbA + D_);
        const float4* qB = (const float4*)(xbB + D_);
        xp0 = qA[0]; xp1 = qA[1]; xq0 = qB[0]; xq1 = qB[1];
    }
    lds_barrier();

    char* Xc = Xb0; char* Xn = Xb1;
    char* Hc = Hb0; char* Hn = Hb1;

#pragma unroll 1
    for (int t = 0; t < T_; ++t) {
        // 1) stage X_{t+1} from prefetch regs
        if (t + 1 < T_) {
            *(bf16x8*)(Xn + lbA) = pk8(xp0, xp1);
            *(bf16x8*)(Xn + lbB) = pk8(xq0, xq1);
        }
        // 2) issue X_{t+2} prefetch (survives the LDS-only barrier)
        if (t + 2 < T_) {
            const float4* qA = (const float4*)(xbA + (t + 2) * D_);
            const float4* qB = (const float4*)(xbB + (t + 2) * D_);
            xp0 = qA[0]; xp1 = qA[1]; xq0 = qB[0]; xq1 = qB[1];
        }

        // accumulators bias-initialized (C-in carries bias)
        f32x4 aR[4], aZ[4], aI[4], aH[4];
#pragma unroll
        for (int mt = 0; mt < 4; ++mt) {
            aR[mt] = (f32x4){brz, brz, brz, brz};
            aZ[mt] = (f32x4){bzz, bzz, bzz, bzz};
            aI[mt] = (f32x4){bin_, bin_, bin_, bin_};
            aH[mt] = (f32x4){bhn_, bhn_, bhn_, bhn_};
        }

        // 3) MFMA — X phase, weights streamed (1-deep pipeline)
        bf16x8 wc0 = LDW(0, 0, 0), wc1 = LDW(0, 1, 0), wc2 = LDW(0, 2, 0);
#pragma unroll
        for (int kt = 0; kt < 4; ++kt) {
            bf16x8 wn0 = wc0, wn1 = wc1, wn2 = wc2;
            if (kt < 3) {
                wn0 = LDW(0, 0, kt + 1); wn1 = LDW(0, 1, kt + 1); wn2 = LDW(0, 2, kt + 1);
            } else if (t > 0) {
                wn0 = LDW(1, 0, 0); wn1 = LDW(1, 1, 0); wn2 = LDW(1, 2, 0);
            }
            const int cb = kt * 64 + l4 * 16;
#pragma unroll
            for (int mt = 0; mt < 4; ++mt) {
                bf16x8 a = t_frag(Xc, mt * 16 + l15, cb);
                aR[mt] = __builtin_amdgcn_mfma_f32_16x16x32_bf16(a, wc0, aR[mt], 0, 0, 0);
                aZ[mt] = __builtin_amdgcn_mfma_f32_16x16x32_bf16(a, wc1, aZ[mt], 0, 0, 0);
                aI[mt] = __builtin_amdgcn_mfma_f32_16x16x32_bf16(a, wc2, aI[mt], 0, 0, 0);
            }
            wc0 = wn0; wc1 = wn1; wc2 = wn2;
        }
        //    MFMA — H phase (skip t=0: h=0 -> gh = bias only, already in C)
        if (t > 0) {
#pragma unroll
            for (int kt = 0; kt < 4; ++kt) {
                bf16x8 wn0 = wc0, wn1 = wc1, wn2 = wc2;
                if (kt < 3) {
                    wn0 = LDW(1, 0, kt + 1); wn1 = LDW(1, 1, kt + 1); wn2 = LDW(1, 2, kt + 1);
                }
                const int cb = kt * 64 + l4 * 16;
#pragma unroll
                for (int mt = 0; mt < 4; ++mt) {
                    bf16x8 a = t_frag(Hc, mt * 16 + l15, cb);
                    aR[mt] = __builtin_amdgcn_mfma_f32_16x16x32_bf16(a, wc0, aR[mt], 0, 0, 0);
                    aZ[mt] = __builtin_amdgcn_mfma_f32_16x16x32_bf16(a, wc1, aZ[mt], 0, 0, 0);
                    aH[mt] = __builtin_amdgcn_mfma_f32_16x16x32_bf16(a, wc2, aH[mt], 0, 0, 0);
                }
                wc0 = wn0; wc1 = wn1; wc2 = wn2;
            }
        }

        // 4) epilogue (lane-local); h_new = n + z*(h-n)
#pragma unroll
        for (int mt = 0; mt < 4; ++mt)
#pragma unroll
            for (int r = 0; r < 4; ++r) {
                float rr = sigm(aR[mt][r]);
                float zz = sigm(aZ[mt][r]);
                float nn = fast_tanh(aI[mt][r] + rr * aH[mt][r]);
                float hold = hm[mt][r];
                float hnew = nn + zz * (hold - nn);
                int lv = (int)((lp[mt] >> (8 * r)) & 0xffu);
                hm[mt][r] = (t < lv) ? hnew : hold;
            }

        // 5) write h_{t+1} -> Hn; 6) LDS-only barrier
        if (t + 1 < T_) {
#pragma unroll
            for (int mt = 0; mt < 4; ++mt) {
#pragma unroll
                for (int rp = 0; rp < 4; rp += 2) {
                    unsigned pk = cvtpk(hm[mt][rp], hm[mt][rp + 1]);
                    int row0 = mt * 16 + l4 * 4 + rp;
                    int row1 = row0 + 1;
                    *(short*)(Hn + row0 * 256 + ((dcol * 2) ^ ((row0 & 7) << 4))) = (short)(pk & 0xffff);
                    *(short*)(Hn + row1 * 256 + ((dcol * 2) ^ ((row1 & 7) << 4))) = (short)(pk >> 16);
                }
            }
            lds_barrier();
            { char* tmp = Xc; Xc = Xn; Xn = tmp; }
            { char* tmp = Hc; Hc = Hn; Hn = tmp; }
        }
    }
#undef LDW

    // final h -> mh (bf16)
#pragma unroll
    for (int mt = 0; mt < 4; ++mt) {
#pragma unroll
        for (int r = 0; r < 4; ++r) {
            int m = m0 + mt * 16 + l4 * 4 + r;
            mh[(size_t)m * 128 + dcol] = f2bf(hm[mt][r]);
        }
    }
}

// ---------------------------------------------------------------------------
// K2 (MFMA): [mi|mh] (32768x256) @ [w_in;w_out]^T -> h_ioT[b][j][e] bf16.
// ---------------------------------------------------------------------------
__global__ __launch_bounds__(512) void k2_mfma(
    const float* __restrict__ mi, const short* __restrict__ mh,
    const float* __restrict__ w_in, const float* __restrict__ b_in,
    const float* __restrict__ w_out, const float* __restrict__ b_out,
    short* __restrict__ hioT)     // [B][256][128] bf16 (in d_out)
{
    __shared__ __align__(16) char As[128 * 64];
    __shared__ __align__(16) char Bs[256 * 64];

    const int tid = threadIdx.x;
    const int l = tid & 63, w = tid >> 6;
    const int l15 = l & 15, l4 = l >> 4;
    const int wr = w >> 1, wc = w & 1;
    const int b  = blockIdx.x;
    const int m0 = b * 128;

    float bj[8];
#pragma unroll
    for (int cf = 0; cf < 8; ++cf) {
        int j = wc * 128 + cf * 16 + l15;
        bj[cf] = (j < 128) ? b_in[j] : b_out[j - 128];
    }

    f32x4 acc[2][8];
#pragma unroll
    for (int rf = 0; rf < 2; ++rf)
#pragma unroll
        for (int cf = 0; cf < 8; ++cf) acc[rf][cf] = (f32x4){0.f,0.f,0.f,0.f};

    const int srow = tid >> 2, sc4 = tid & 3;
    const int brow = tid >> 1, bh  = tid & 1;

#pragma unroll 1
    for (int kt = 0; kt < 8; ++kt) {
        if (kt < 4) {
            *(bf16x8*)(As + SLADDR(srow, sc4)) =
                cvt8(mi + (size_t)(m0 + srow) * 128 + kt * 32 + sc4 * 8);
        } else {
            *(bf16x8*)(As + SLADDR(srow, sc4)) =
                *(const bf16x8*)(mh + (size_t)(m0 + srow) * 128 + (kt - 4) * 32 + sc4 * 8);
        }
        {
            const float* wsrc = (brow < 128)
                ? (w_in  + (size_t)brow * 256 + kt * 32 + bh * 16)
                : (w_out + (size_t)(brow - 128) * 256 + kt * 32 + bh * 16);
            *(bf16x8*)(Bs + SLADDR(brow, bh * 2    )) = cvt8(wsrc);
            *(bf16x8*)(Bs + SLADDR(brow, bh * 2 + 1)) = cvt8(wsrc + 8);
        }
        __syncthreads();

        bf16x8 af[2], bfr[8];
#pragma unroll
        for (int rf = 0; rf < 2; ++rf)
            af[rf] = *(const bf16x8*)(As + SLADDR(wr * 32 + rf * 16 + l15, l4));
#pragma unroll
        for (int cf = 0; cf < 8; ++cf)
            bfr[cf] = *(const bf16x8*)(Bs + SLADDR(wc * 128 + cf * 16 + l15, l4));
#pragma unroll
        for (int rf = 0; rf < 2; ++rf)
#pragma unroll
            for (int cf = 0; cf < 8; ++cf)
                acc[rf][cf] = __builtin_amdgcn_mfma_f32_16x16x32_bf16(af[rf], bfr[cf], acc[rf][cf], 0, 0, 0);
        __syncthreads();
    }

#pragma unroll
    for (int rf = 0; rf < 2; ++rf)
#pragma unroll
        for (int cf = 0; cf < 8; ++cf) {
            int j  = wc * 128 + cf * 16 + l15;
            int e0 = wr * 32 + rf * 16 + l4 * 4;
            s16x4 s;
#pragma unroll
            for (int r = 0; r < 4; ++r) s[r] = f2bf(acc[rf][cf][r] + bj[cf]);
            *(s16x4*)(hioT + ((size_t)b * 256 + j) * 128 + e0) = s;
        }
}

// ---------------------------------------------------------------------------
// K3a (MFMA): per-batch einsum.
// ---------------------------------------------------------------------------
__global__ __launch_bounds__(512) void k3a_einsum(
    const float* __restrict__ A, const short* __restrict__ hioT,
    const float* __restrict__ b_iah, const float* __restrict__ b_ioh,
    short* __restrict__ inputs)    // [M][256] bf16 (ws)
{
    __shared__ __align__(16) char As0[128 * 64];
    __shared__ __align__(16) char As1[128 * 64];
    __shared__ __align__(16) char Bs [256 * 64];

    const int tid = threadIdx.x;
    const int l = tid & 63, w = tid >> 6;
    const int l15 = l & 15, l4 = l >> 4;
    const int wr = w >> 1, wc = w & 1;
    const int b  = blockIdx.x;

    float bj[8];
#pragma unroll
    for (int cf = 0; cf < 8; ++cf) {
        int j = wc * 128 + cf * 16 + l15;
        bj[cf] = (j < 128) ? b_iah[j] : b_ioh[j - 128];
    }

    f32x4 acc[2][8];
#pragma unroll
    for (int rf = 0; rf < 2; ++rf)
#pragma unroll
        for (int cf = 0; cf < 8; ++cf) acc[rf][cf] = (f32x4){0.f,0.f,0.f,0.f};

    const int srow = tid >> 2, sc4 = tid & 3;
    const int brow = tid >> 1, bh  = tid & 1;
    const float* Ab = A + (size_t)b * 128 * 256;

#pragma unroll 1
    for (int kt = 0; kt < 4; ++kt) {
        *(bf16x8*)(As0 + SLADDR(srow, sc4)) = cvt8(Ab + (size_t)srow * 256 +       kt * 32 + sc4 * 8);
        *(bf16x8*)(As1 + SLADDR(srow, sc4)) = cvt8(Ab + (size_t)srow * 256 + 128 + kt * 32 + sc4 * 8);
        {
            const short* hs = hioT + ((size_t)b * 256 + brow) * 128 + kt * 32 + bh * 16;
            *(bf16x8*)(Bs + SLADDR(brow, bh * 2    )) = *(const bf16x8*)hs;
            *(bf16x8*)(Bs + SLADDR(brow, bh * 2 + 1)) = *(const bf16x8*)(hs + 8);
        }
        __syncthreads();

        const char* Asel = wc ? As1 : As0;
        bf16x8 af[2], bfr[8];
#pragma unroll
        for (int rf = 0; rf < 2; ++rf)
            af[rf] = *(const bf16x8*)(Asel + SLADDR(wr * 32 + rf * 16 + l15, l4));
#pragma unroll
        for (int cf = 0; cf < 8; ++cf)
            bfr[cf] = *(const bf16x8*)(Bs + SLADDR(wc * 128 + cf * 16 + l15, l4));
#pragma unroll
        for (int rf = 0; rf < 2; ++rf)
#pragma unroll
            for (int cf = 0; cf < 8; ++cf)
                acc[rf][cf] = __builtin_amdgcn_mfma_f32_16x16x32_bf16(af[rf], bfr[cf], acc[rf][cf], 0, 0, 0);
        __syncthreads();
    }

#pragma unroll
    for (int rf = 0; rf < 2; ++rf)
#pragma unroll
        for (int cf = 0; cf < 8; ++cf) {
            int j = wc * 128 + cf * 16 + l15;
#pragma unroll
            for (int r = 0; r < 4; ++r) {
                int m = b * 128 + wr * 32 + rf * 16 + l4 * 4 + r;
                inputs[(size_t)m * 256 + j] = f2bf(acc[rf][cf][r] + bj[cf]);
            }
        }
}

// ---------------------------------------------------------------------------
// K3b (MFMA): gate GEMM + epilogue.
// ---------------------------------------------------------------------------
__global__ __launch_bounds__(512) void k3b_gate(
    const short* __restrict__ inputs, const float* __restrict__ hidden,
    const float* __restrict__ wih, const float* __restrict__ whh,
    const float* __restrict__ bih, const float* __restrict__ bhh,
    float* __restrict__ out)
{
    __shared__ __align__(16) char As[128 * 64];
    __shared__ __align__(16) char Bs[384 * 64];

    const int tid = threadIdx.x;
    const int l = tid & 63, w = tid >> 6;
    const int l15 = l & 15, l4 = l >> 4;
    const int wr = w >> 1, wc = w & 1;
    const int m0 = blockIdx.x * 128;

    float br[4], bz[4], bi[4], bh_[4];
#pragma unroll
    for (int p = 0; p < 4; ++p) {
        int d = (wc * 4 + p) * 16 + l15;
        br[p] = bih[d]       + bhh[d];
        bz[p] = bih[128 + d] + bhh[128 + d];
        bi[p] = bih[256 + d];
        bh_[p]= bhh[256 + d];
    }

    f32x4 aR[2][4], aZ[2][4], aI[2][4], aH[2][4];
#pragma unroll
    for (int rf = 0; rf < 2; ++rf)
#pragma unroll
        for (int p = 0; p < 4; ++p) {
            aR[rf][p] = (f32x4){0.f,0.f,0.f,0.f};
            aZ[rf][p] = (f32x4){0.f,0.f,0.f,0.f};
            aI[rf][p] = (f32x4){0.f,0.f,0.f,0.f};
            aH[rf][p] = (f32x4){0.f,0.f,0.f,0.f};
        }

    const int srow = tid >> 2, sc4 = tid & 3;

#pragma unroll 1
    for (int kt = 0; kt < 12; ++kt) {
        if (kt < 8) {
            const short* src = inputs + (size_t)(m0 + srow) * 256 + kt * 32 + sc4 * 8;
            *(bf16x8*)(As + SLADDR(srow, sc4)) = *(const bf16x8*)src;
        } else {
            const float* src = hidden + (size_t)(m0 + srow) * 128 + (kt - 8) * 32 + sc4 * 8;
            *(bf16x8*)(As + SLADDR(srow, sc4)) = cvt8(src);
        }
#pragma unroll
        for (int i = 0; i < 3; ++i) {
            int c = tid + 512 * i;
            int row = c >> 2, ch = c & 3;
            const float* wsrc = (kt < 8)
                ? (wih + (size_t)row * 256 + kt * 32 + ch * 8)
                : (whh + (size_t)row * 128 + (kt - 8) * 32 + ch * 8);
            *(bf16x8*)(Bs + SLADDR(row, ch)) = cvt8(wsrc);
        }
        __syncthreads();

        bf16x8 a0 = *(const bf16x8*)(As + SLADDR(wr * 32 +      l15, l4));
        bf16x8 a1 = *(const bf16x8*)(As + SLADDR(wr * 32 + 16 + l15, l4));
#pragma unroll
        for (int p = 0; p < 4; ++p) {
            int jb = (wc * 4 + p) * 16 + l15;
            bf16x8 bR = *(const bf16x8*)(Bs + SLADDR(      jb, l4));
            bf16x8 bZ = *(const bf16x8*)(Bs + SLADDR(128 + jb, l4));
            bf16x8 bN = *(const bf16x8*)(Bs + SLADDR(256 + jb, l4));
            aR[0][p] = __builtin_amdgcn_mfma_f32_16x16x32_bf16(a0, bR, aR[0][p], 0, 0, 0);
            aR[1][p] = __builtin_amdgcn_mfma_f32_16x16x32_bf16(a1, bR, aR[1][p], 0, 0, 0);
            aZ[0][p] = __builtin_amdgcn_mfma_f32_16x16x32_bf16(a0, bZ, aZ[0][p], 0, 0, 0);
            aZ[1][p] = __builtin_amdgcn_mfma_f32_16x16x32_bf16(a1, bZ, aZ[1][p], 0, 0, 0);
            if (kt < 8) {
                aI[0][p] = __builtin_amdgcn_mfma_f32_16x16x32_bf16(a0, bN, aI[0][p], 0, 0, 0);
                aI[1][p] = __builtin_amdgcn_mfma_f32_16x16x32_bf16(a1, bN, aI[1][p], 0, 0, 0);
            } else {
                aH[0][p] = __builtin_amdgcn_mfma_f32_16x16x32_bf16(a0, bN, aH[0][p], 0, 0, 0);
                aH[1][p] = __builtin_amdgcn_mfma_f32_16x16x32_bf16(a1, bN, aH[1][p], 0, 0, 0);
            }
        }
        __syncthreads();
    }

#pragma unroll
    for (int rf = 0; rf < 2; ++rf)
#pragma unroll
        for (int p = 0; p < 4; ++p) {
            int d = (wc * 4 + p) * 16 + l15;
#pragma unroll
            for (int r = 0; r < 4; ++r) {
                int m = m0 + wr * 32 + rf * 16 + l4 * 4 + r;
                float hv = hidden[(size_t)m * 128 + d];
                float rg = sigm(aR[rf][p][r] + br[p]);
                float zg = sigm(aZ[rf][p][r] + bz[p]);
                float ng = fast_tanh(aI[rf][p][r] + bi[p] + rg * (aH[rf][p][r] + bh_[p]));
                out[(size_t)m * 128 + d] = (1.f - zg) * hv + zg * ng;
            }
        }
}

// ---------------------------------------------------------------------------
extern "C" void kernel_launch(void* const* d_in, const int* in_sizes, int n_in,
                              void* d_out, int out_size, void* d_ws, size_t ws_size,
                              hipStream_t stream) {
    const float* A     = (const float*)d_in[0];
    const float* hidden= (const float*)d_in[1];
    const float* mi    = (const float*)d_in[2];
    const float* xa    = (const float*)d_in[3];
    const int*   len   = (const int*)  d_in[4];
    const float* gwih  = (const float*)d_in[5];
    const float* gwhh  = (const float*)d_in[6];
    const float* gbih  = (const float*)d_in[7];
    const float* gbhh  = (const float*)d_in[8];
    const float* wih   = (const float*)d_in[9];
    const float* whh   = (const float*)d_in[10];
    const float* bih   = (const float*)d_in[11];
    const float* bhh   = (const float*)d_in[12];
    const float* biah  = (const float*)d_in[13];
    const float* bioh  = (const float*)d_in[14];
    const float* w_in  = (const float*)d_in[15];
    const float* b_in  = (const float*)d_in[16];
    const float* w_out = (const float*)d_in[17];
    const float* b_out = (const float*)d_in[18];

    float* out = (float*)d_out;
    // ws layout (25.4 MB):
    //   [0, 8.39 MB):      mh bf16 [M][128]       (k1 -> k2)
    //   [8.39, 25.2 MB):   inputs bf16 [M][256]   (k3a -> k3b)
    //   [25.2 MB, +192KB): wfrag bf16 [192*64*8]  (k0w -> k1, L2-resident)
    // d_out doubles as h_ioT bf16 [B][256][128]   (k2 -> k3a), overwritten by k3b.
    short* mh     = (short*)d_ws;
    short* inputs = (short*)((char*)d_ws + (size_t)M_ * D_ * 2);
    short* wfrag  = (short*)((char*)d_ws + (size_t)M_ * D_ * 2 + (size_t)M_ * 256 * 2);
    short* hioT   = (short*)d_out;

    k0w_pack   <<<24,      512, 0, stream>>>(gwih, gwhh, wfrag);
    k1_gru_mfma<<<M_ / 64, 512, 0, stream>>>(xa, len, wfrag, gbih, gbhh, mh);
    k2_mfma    <<<B_,      512, 0, stream>>>(mi, mh, w_in, b_in, w_out, b_out, hioT);
    k3a_einsum <<<B_,      512, 0, stream>>>(A, hioT, biah, bioh, inputs);
    k3b_gate   <<<M_/128,  512, 0, stream>>>(inputs, hidden, wih, whh, bih, bhh, out);
}

// Round 10
// 304.397 us; speedup vs baseline: 2.2246x; 2.2246x over previous
//
#include <hip/hip_runtime.h>
#include <math.h>

#define B_ 256
#define E_ 128
#define N_ 128
#define T_ 20
#define D_ 128
#define M_ (B_*E_)   // 32768 sequences

typedef __attribute__((ext_vector_type(8))) short bf16x8;
typedef __attribute__((ext_vector_type(4))) short s16x4;
typedef __attribute__((ext_vector_type(4))) float f32x4;
typedef __attribute__((ext_vector_type(4))) unsigned u32x4;

__device__ __forceinline__ float sigm(float x) { return 1.0f / (1.0f + __expf(-x)); }
__device__ __forceinline__ float fast_tanh(float x) {
    float e = __expf(2.f * x);
    return 1.f - 2.f / (e + 1.f);
}
__device__ __forceinline__ short f2bf(float f) {   // RNE float->bf16 (scalar)
    unsigned u = __builtin_bit_cast(unsigned, f);
    u += 0x7fffu + ((u >> 16) & 1u);
    return (short)(u >> 16);
}
// HW packed convert: 2 f32 -> 2 bf16 in one instruction (RNE).
__device__ __forceinline__ unsigned cvtpk(float lo, float hi) {
    unsigned r;
    asm("v_cvt_pk_bf16_f32 %0, %1, %2" : "=v"(r) : "v"(lo), "v"(hi));
    return r;
}
__device__ __forceinline__ bf16x8 pk8(float4 a, float4 b) {
    u32x4 u = { cvtpk(a.x,a.y), cvtpk(a.z,a.w), cvtpk(b.x,b.y), cvtpk(b.z,b.w) };
    return __builtin_bit_cast(bf16x8, u);
}
__device__ __forceinline__ bf16x8 cvt8(const float* __restrict__ p) {
    float4 u = *(const float4*)p;
    float4 v = *(const float4*)(p + 4);
    return pk8(u, v);
}

// [rows][32k] bf16 slice, 64 B/row; chunk-XOR swizzle.
#define SLADDR(row, chunk) ((row) * 64 + ((((chunk) ^ ((row) >> 1)) & 3) << 4))

// [rows][128 cols bf16] tile, 256 B/row, byte-XOR swizzle.
__device__ __forceinline__ bf16x8 t_frag(const char* base, int row, int cb) {
    return *(const bf16x8*)(base + row * 256 + (cb ^ ((row & 7) << 4)));
}
// [rows][256 cols bf16] tile, 512 B/row, byte-XOR swizzle.
__device__ __forceinline__ bf16x8 t_frag512(const char* base, int row, int cb) {
    return *(const bf16x8*)(base + row * 512 + (cb ^ ((row & 7) << 4)));
}

// LDS-only barrier: drain LDS ops, sync, but DON'T drain vmcnt.
__device__ __forceinline__ void lds_barrier() {
    asm volatile("s_waitcnt lgkmcnt(0)" ::: "memory");
    __builtin_amdgcn_s_barrier();
    asm volatile("" ::: "memory");
}

// ---------------------------------------------------------------------------
// K0: deterministic counting sort of sequence indices by len (bins 1..20).
// (byte-identical to round 8 — proven)
// ---------------------------------------------------------------------------
__global__ __launch_bounds__(1024) void k0_sort(
    const int* __restrict__ len, int* __restrict__ perm)
{
    __shared__ int wavehist[16][21];
    __shared__ int wavecur [16][21];
    const int tid  = threadIdx.x;
    const int lane = tid & 63;
    const int w    = tid >> 6;

    int cnt = 0;
#pragma unroll 1
    for (int it = 0; it < 32; ++it) {
        int v = len[w * 2048 + it * 64 + lane];
#pragma unroll
        for (int b = 1; b <= 20; ++b) {
            unsigned long long mask = __ballot(v == b);
            if (lane == b - 1) cnt += __popcll(mask);
        }
    }
    if (lane < 20) wavehist[w][lane + 1] = cnt;
    __syncthreads();

    if (tid == 0) {
        int run = 0;
        for (int b = 1; b <= 20; ++b)
            for (int wv = 0; wv < 16; ++wv) {
                int c = wavehist[wv][b];
                wavecur[wv][b] = run;
                run += c;
            }
    }
    __syncthreads();

#pragma unroll 1
    for (int it = 0; it < 32; ++it) {
        int idx = w * 2048 + it * 64 + lane;
        int v = len[idx];
#pragma unroll 1
        for (int b = 1; b <= 20; ++b) {
            unsigned long long mask = __ballot(v == b);
            if (mask) {
                int base = 0;
                if (lane == 0) {
                    base = wavecur[w][b];
                    wavecur[w][b] = base + __popcll(mask);
                }
                base = __shfl(base, 0, 64);
                if (v == b) {
                    int rank = __popcll(mask & ((1ull << lane) - 1ull));
                    perm[base + rank] = idx;
                }
            }
        }
    }
}

// ---------------------------------------------------------------------------
// K1: persistent MFMA micro-GRU over length-sorted chunks.
// (byte-identical to round 8 — proven: 512 thr / 8 waves / 64 seqs / mt=4,
// ~128 VGPR + 64 AGPR, no spill)
// ---------------------------------------------------------------------------
__global__ __launch_bounds__(512, 2) void k1_gru_mfma(
    const float* __restrict__ xa, const int* __restrict__ len,
    const int* __restrict__ perm,
    const float* __restrict__ wih, const float* __restrict__ whh,
    const float* __restrict__ bih, const float* __restrict__ bhh,
    short* __restrict__ mh)        // bf16 [M][128]
{
    __shared__ __align__(16) char Xb0[64 * 256];
    __shared__ __align__(16) char Xb1[64 * 256];
    __shared__ __align__(16) char Hb0[64 * 256];
    __shared__ __align__(16) char Hb1[64 * 256];
    __shared__ int pidx[64];
    __shared__ int lens_s[64];
    __shared__ int lmax_s;

    const int tid = threadIdx.x;
    const int l   = tid & 63;
    const int w   = tid >> 6;
    const int l15 = l & 15;
    const int l4  = l >> 4;

    bf16x8 wf[2][3][4];
#pragma unroll
    for (int s = 0; s < 2; ++s) {
        const float* W = s ? whh : wih;
#pragma unroll
        for (int g = 0; g < 3; ++g) {
            int grow = g * 128 + w * 16 + l15;
#pragma unroll
            for (int kt = 0; kt < 4; ++kt)
                wf[s][g][kt] = cvt8(W + (size_t)grow * 128 + kt * 32 + l4 * 8);
        }
    }

    const int dcol = w * 16 + l15;
    const float brz = bih[dcol]       + bhh[dcol];
    const float bzz = bih[128 + dcol] + bhh[128 + dcol];
    const float bin_= bih[256 + dcol];
    const float bhn_= bhh[256 + dcol];

    const int sr0 = tid >> 4;
    const int sc8 = (tid & 15) * 8;
    const int lbA = sr0 * 256 + ((sc8 * 2) ^ ((sr0 & 7) << 4));
    const int lbB = (sr0 + 32) * 256 + ((sc8 * 2) ^ (((sr0 + 32) & 7) << 4));

#pragma unroll 1
    for (int pass = 0; pass < 2; ++pass) {
        const int chunk = pass ? (511 - (int)blockIdx.x) : (int)blockIdx.x;

        __syncthreads();
        if (tid < 64) {
            int p = perm[chunk * 64 + tid];
            pidx[tid]   = p;
            lens_s[tid] = len[p];
        }
        __syncthreads();
        if (tid == 0) {
            int mx = 0;
            for (int i = 0; i < 64; ++i) mx = max(mx, lens_s[i]);
            lmax_s = mx;
        }

        int lenv[16];
#pragma unroll
        for (int mt = 0; mt < 4; ++mt)
#pragma unroll
            for (int r = 0; r < 4; ++r)
                lenv[mt * 4 + r] = lens_s[mt * 16 + l4 * 4 + r];

        const int rA = pidx[sr0];
        const int rB = pidx[sr0 + 32];
        const float* xbA = xa + (size_t)rA * (T_ * D_) + sc8;
        const float* xbB = xa + (size_t)rB * (T_ * D_) + sc8;

        {
            const float4* pA = (const float4*)xbA;
            const float4* pB = (const float4*)xbB;
            *(bf16x8*)(Xb0 + lbA) = pk8(pA[0], pA[1]);
            *(bf16x8*)(Xb0 + lbB) = pk8(pB[0], pB[1]);
        }
        float4 xa0, xa1, xb0v, xb1v;
        {
            const float4* qA = (const float4*)(xbA + D_);
            const float4* qB = (const float4*)(xbB + D_);
            xa0 = qA[0]; xa1 = qA[1]; xb0v = qB[0]; xb1v = qB[1];
        }
        __syncthreads();
        const int Lmax = lmax_s;

        float hm[4][4];
#pragma unroll
        for (int mt = 0; mt < 4; ++mt)
#pragma unroll
            for (int r = 0; r < 4; ++r) hm[mt][r] = 0.f;

        char* Xc = Xb0; char* Xn = Xb1;
        char* Hc = Hb0; char* Hn = Hb1;

#pragma unroll 1
        for (int t = 0; t < Lmax; ++t) {
            if (t + 1 < Lmax) {
                *(bf16x8*)(Xn + lbA) = pk8(xa0, xa1);
                *(bf16x8*)(Xn + lbB) = pk8(xb0v, xb1v);
            }
            if (t + 2 < Lmax) {
                const float4* qA = (const float4*)(xbA + (t + 2) * D_);
                const float4* qB = (const float4*)(xbB + (t + 2) * D_);
                xa0 = qA[0]; xa1 = qA[1]; xb0v = qB[0]; xb1v = qB[1];
            }

            f32x4 aR[4], aZ[4], aI[4], aH[4];
#pragma unroll
            for (int mt = 0; mt < 4; ++mt) {
                aR[mt] = (f32x4){brz, brz, brz, brz};
                aZ[mt] = (f32x4){bzz, bzz, bzz, bzz};
                aI[mt] = (f32x4){bin_, bin_, bin_, bin_};
                aH[mt] = (f32x4){bhn_, bhn_, bhn_, bhn_};
            }

#pragma unroll
            for (int kt = 0; kt < 4; ++kt) {
                const int cb = kt * 64 + l4 * 16;
#pragma unroll
                for (int mt = 0; mt < 4; ++mt) {
                    bf16x8 a = t_frag(Xc, mt * 16 + l15, cb);
                    aR[mt] = __builtin_amdgcn_mfma_f32_16x16x32_bf16(a, wf[0][0][kt], aR[mt], 0, 0, 0);
                    aZ[mt] = __builtin_amdgcn_mfma_f32_16x16x32_bf16(a, wf[0][1][kt], aZ[mt], 0, 0, 0);
                    aI[mt] = __builtin_amdgcn_mfma_f32_16x16x32_bf16(a, wf[0][2][kt], aI[mt], 0, 0, 0);
                }
            }
            if (t > 0) {
#pragma unroll
                for (int kt = 0; kt < 4; ++kt) {
                    const int cb = kt * 64 + l4 * 16;
#pragma unroll
                    for (int mt = 0; mt < 4; ++mt) {
                        bf16x8 a = t_frag(Hc, mt * 16 + l15, cb);
                        aR[mt] = __builtin_amdgcn_mfma_f32_16x16x32_bf16(a, wf[1][0][kt], aR[mt], 0, 0, 0);
                        aZ[mt] = __builtin_amdgcn_mfma_f32_16x16x32_bf16(a, wf[1][1][kt], aZ[mt], 0, 0, 0);
                        aH[mt] = __builtin_amdgcn_mfma_f32_16x16x32_bf16(a, wf[1][2][kt], aH[mt], 0, 0, 0);
                    }
                }
            }

#pragma unroll
            for (int mt = 0; mt < 4; ++mt)
#pragma unroll
                for (int r = 0; r < 4; ++r) {
                    float rr = sigm(aR[mt][r]);
                    float zz = sigm(aZ[mt][r]);
                    float nn = fast_tanh(aI[mt][r] + rr * aH[mt][r]);
                    float hold = hm[mt][r];
                    float hnew = nn + zz * (hold - nn);
                    hm[mt][r] = (t < lenv[mt * 4 + r]) ? hnew : hold;
                }

            if (t + 1 < Lmax) {
#pragma unroll
                for (int mt = 0; mt < 4; ++mt) {
#pragma unroll
                    for (int rp = 0; rp < 4; rp += 2) {
                        unsigned pk = cvtpk(hm[mt][rp], hm[mt][rp + 1]);
                        int row0 = mt * 16 + l4 * 4 + rp;
                        int row1 = row0 + 1;
                        *(short*)(Hn + row0 * 256 + ((dcol * 2) ^ ((row0 & 7) << 4))) = (short)(pk & 0xffff);
                        *(short*)(Hn + row1 * 256 + ((dcol * 2) ^ ((row1 & 7) << 4))) = (short)(pk >> 16);
                    }
                }
                lds_barrier();
                { char* tmp = Xc; Xc = Xn; Xn = tmp; }
                { char* tmp = Hc; Hc = Hn; Hn = tmp; }
            }
        }

#pragma unroll
        for (int mt = 0; mt < 4; ++mt) {
#pragma unroll
            for (int r = 0; r < 4; ++r) {
                int m = pidx[mt * 16 + l4 * 4 + r];
                mh[(size_t)m * 128 + dcol] = f2bf(hm[mt][r]);
            }
        }
    }
}

// ---------------------------------------------------------------------------
// K23 (fused k2 + k3a + k3b): one block per batch b, 512 threads, all
// intermediates LDS-resident:
//   P1: hioT_lds[256][128] = ([mi|mh] @ [w_in;w_out]^T + bias)^T   (bf16)
//   P2: inputs_lds[128][256] = [A_in @ h_in | A_out @ h_out] + bias (bf16)
//   P3: gates GEMM (r/z K=384 over [inputs|hidden], n split) + epilogue -> out
// LDS: HIO 64K (reused as hidden-staging in P3) + INP 64K + STG 24K = 152 KB.
// Removes 2 launches + 67 MB global round-trip vs separate k2/k3a/k3b.
// ---------------------------------------------------------------------------
__global__ __launch_bounds__(512) void k23_fused(
    const float* __restrict__ A, const float* __restrict__ hidden,
    const float* __restrict__ mi, const short* __restrict__ mh,
    const float* __restrict__ w_in, const float* __restrict__ b_in,
    const float* __restrict__ w_out, const float* __restrict__ b_out,
    const float* __restrict__ b_iah, const float* __restrict__ b_ioh,
    const float* __restrict__ wih, const float* __restrict__ whh,
    const float* __restrict__ bih, const float* __restrict__ bhh,
    float* __restrict__ out)
{
    __shared__ __align__(16) char HIO[64 * 1024];  // P1 out / P2 B-src; P3: hidden staging
    __shared__ __align__(16) char INP[64 * 1024];  // P2 out / P3 A-src
    __shared__ __align__(16) char STG[24 * 1024];  // per-kt staging (As/Bs)

    const int tid = threadIdx.x;
    const int l = tid & 63, w = tid >> 6;
    const int l15 = l & 15, l4 = l >> 4;
    const int wr = w >> 1, wc = w & 1;
    const int b  = blockIdx.x;
    const int m0 = b * 128;

    char* As  = STG;              // 8 KB
    char* Bs  = STG + 8 * 1024;   // 16 KB (P1); P3 uses STG as 24 KB Bs
    const int srow = tid >> 2, sc4 = tid & 3;
    const int brow = tid >> 1, bh  = tid & 1;

    // ================= Phase 1: k2 -> hioT_lds =================
    {
        float bj[8];
#pragma unroll
        for (int cf = 0; cf < 8; ++cf) {
            int j = wc * 128 + cf * 16 + l15;
            bj[cf] = (j < 128) ? b_in[j] : b_out[j - 128];
        }
        f32x4 acc[2][8];
#pragma unroll
        for (int rf = 0; rf < 2; ++rf)
#pragma unroll
            for (int cf = 0; cf < 8; ++cf) acc[rf][cf] = (f32x4){0.f,0.f,0.f,0.f};

#pragma unroll 1
        for (int kt = 0; kt < 8; ++kt) {
            if (kt < 4) {
                *(bf16x8*)(As + SLADDR(srow, sc4)) =
                    cvt8(mi + (size_t)(m0 + srow) * 128 + kt * 32 + sc4 * 8);
            } else {
                *(bf16x8*)(As + SLADDR(srow, sc4)) =
                    *(const bf16x8*)(mh + (size_t)(m0 + srow) * 128 + (kt - 4) * 32 + sc4 * 8);
            }
            {
                const float* wsrc = (brow < 128)
                    ? (w_in  + (size_t)brow * 256 + kt * 32 + bh * 16)
                    : (w_out + (size_t)(brow - 128) * 256 + kt * 32 + bh * 16);
                *(bf16x8*)(Bs + SLADDR(brow, bh * 2    )) = cvt8(wsrc);
                *(bf16x8*)(Bs + SLADDR(brow, bh * 2 + 1)) = cvt8(wsrc + 8);
            }
            __syncthreads();
            bf16x8 af[2], bfr[8];
#pragma unroll
            for (int rf = 0; rf < 2; ++rf)
                af[rf] = *(const bf16x8*)(As + SLADDR(wr * 32 + rf * 16 + l15, l4));
#pragma unroll
            for (int cf = 0; cf < 8; ++cf)
                bfr[cf] = *(const bf16x8*)(Bs + SLADDR(wc * 128 + cf * 16 + l15, l4));
#pragma unroll
            for (int rf = 0; rf < 2; ++rf)
#pragma unroll
                for (int cf = 0; cf < 8; ++cf)
                    acc[rf][cf] = __builtin_amdgcn_mfma_f32_16x16x32_bf16(af[rf], bfr[cf], acc[rf][cf], 0, 0, 0);
            __syncthreads();
        }

        // write hioT_lds[j][e], 256B rows, row-XOR swizzle (t_frag layout)
#pragma unroll
        for (int rf = 0; rf < 2; ++rf)
#pragma unroll
            for (int cf = 0; cf < 8; ++cf) {
                int j  = wc * 128 + cf * 16 + l15;
                int e0 = wr * 32 + rf * 16 + l4 * 4;
                s16x4 s;
#pragma unroll
                for (int r = 0; r < 4; ++r) s[r] = f2bf(acc[rf][cf][r] + bj[cf]);
                *(s16x4*)(HIO + j * 256 + ((e0 * 2) ^ ((j & 7) << 4))) = s;
            }
        __syncthreads();
    }

    // ================= Phase 2: k3a -> inputs_lds =================
    {
        char* As0 = STG;              // 8 KB
        char* As1 = STG + 8 * 1024;   // 8 KB
        float bj[8];
#pragma unroll
        for (int cf = 0; cf < 8; ++cf) {
            int j = wc * 128 + cf * 16 + l15;
            bj[cf] = (j < 128) ? b_iah[j] : b_ioh[j - 128];
        }
        f32x4 acc[2][8];
#pragma unroll
        for (int rf = 0; rf < 2; ++rf)
#pragma unroll
            for (int cf = 0; cf < 8; ++cf) acc[rf][cf] = (f32x4){0.f,0.f,0.f,0.f};

        const float* Ab = A + (size_t)b * 128 * 256;
#pragma unroll 1
        for (int kt = 0; kt < 4; ++kt) {
            *(bf16x8*)(As0 + SLADDR(srow, sc4)) = cvt8(Ab + (size_t)srow * 256 +       kt * 32 + sc4 * 8);
            *(bf16x8*)(As1 + SLADDR(srow, sc4)) = cvt8(Ab + (size_t)srow * 256 + 128 + kt * 32 + sc4 * 8);
            __syncthreads();
            const char* Asel = wc ? As1 : As0;
            bf16x8 af[2], bfr[8];
#pragma unroll
            for (int rf = 0; rf < 2; ++rf)
                af[rf] = *(const bf16x8*)(Asel + SLADDR(wr * 32 + rf * 16 + l15, l4));
#pragma unroll
            for (int cf = 0; cf < 8; ++cf)
                bfr[cf] = t_frag(HIO, wc * 128 + cf * 16 + l15, kt * 64 + l4 * 16);
#pragma unroll
            for (int rf = 0; rf < 2; ++rf)
#pragma unroll
                for (int cf = 0; cf < 8; ++cf)
                    acc[rf][cf] = __builtin_amdgcn_mfma_f32_16x16x32_bf16(af[rf], bfr[cf], acc[rf][cf], 0, 0, 0);
            __syncthreads();
        }

        // write inputs_lds[n][j], 512B rows, row-XOR swizzle
#pragma unroll
        for (int rf = 0; rf < 2; ++rf)
#pragma unroll
            for (int cf = 0; cf < 8; ++cf) {
                int j = wc * 128 + cf * 16 + l15;
#pragma unroll
                for (int r = 0; r < 4; ++r) {
                    int n = wr * 32 + rf * 16 + l4 * 4 + r;
                    *(short*)(INP + n * 512 + ((j * 2) ^ ((n & 7) << 4))) = f2bf(acc[rf][cf][r] + bj[cf]);
                }
            }
        __syncthreads();
    }

    // ================= Phase 3: k3b -> out =================
    {
        char* Bs3 = STG;   // 24 KB (384 rows x 64B)
        char* HID = HIO;   // 8 KB reuse (hidden staging, hioT dead now)

        float br[4], bz[4], bi[4], bh_[4];
#pragma unroll
        for (int p = 0; p < 4; ++p) {
            int d = (wc * 4 + p) * 16 + l15;
            br[p] = bih[d]       + bhh[d];
            bz[p] = bih[128 + d] + bhh[128 + d];
            bi[p] = bih[256 + d];
            bh_[p]= bhh[256 + d];
        }
        f32x4 aR[2][4], aZ[2][4], aI[2][4], aH[2][4];
#pragma unroll
        for (int rf = 0; rf < 2; ++rf)
#pragma unroll
            for (int p = 0; p < 4; ++p) {
                aR[rf][p] = (f32x4){0.f,0.f,0.f,0.f};
                aZ[rf][p] = (f32x4){0.f,0.f,0.f,0.f};
                aI[rf][p] = (f32x4){0.f,0.f,0.f,0.f};
                aH[rf][p] = (f32x4){0.f,0.f,0.f,0.f};
            }

#pragma unroll 1
        for (int kt = 0; kt < 12; ++kt) {
            if (kt >= 8) {
                const float* src = hidden + (size_t)(m0 + srow) * 128 + (kt - 8) * 32 + sc4 * 8;
                *(bf16x8*)(HID + SLADDR(srow, sc4)) = cvt8(src);
            }
#pragma unroll
            for (int i = 0; i < 3; ++i) {
                int c = tid + 512 * i;
                int row = c >> 2, ch = c & 3;
                const float* wsrc = (kt < 8)
                    ? (wih + (size_t)row * 256 + kt * 32 + ch * 8)
                    : (whh + (size_t)row * 128 + (kt - 8) * 32 + ch * 8);
                *(bf16x8*)(Bs3 + SLADDR(row, ch)) = cvt8(wsrc);
            }
            __syncthreads();

            bf16x8 a0, a1;
            if (kt < 8) {
                const int cb = kt * 64 + l4 * 16;
                a0 = t_frag512(INP, wr * 32 +      l15, cb);
                a1 = t_frag512(INP, wr * 32 + 16 + l15, cb);
            } else {
                a0 = *(const bf16x8*)(HID + SLADDR(wr * 32 +      l15, l4));
                a1 = *(const bf16x8*)(HID + SLADDR(wr * 32 + 16 + l15, l4));
            }
#pragma unroll
            for (int p = 0; p < 4; ++p) {
                int jb = (wc * 4 + p) * 16 + l15;
                bf16x8 bR = *(const bf16x8*)(Bs3 + SLADDR(      jb, l4));
                bf16x8 bZ = *(const bf16x8*)(Bs3 + SLADDR(128 + jb, l4));
                bf16x8 bN = *(const bf16x8*)(Bs3 + SLADDR(256 + jb, l4));
                aR[0][p] = __builtin_amdgcn_mfma_f32_16x16x32_bf16(a0, bR, aR[0][p], 0, 0, 0);
                aR[1][p] = __builtin_amdgcn_mfma_f32_16x16x32_bf16(a1, bR, aR[1][p], 0, 0, 0);
                aZ[0][p] = __builtin_amdgcn_mfma_f32_16x16x32_bf16(a0, bZ, aZ[0][p], 0, 0, 0);
                aZ[1][p] = __builtin_amdgcn_mfma_f32_16x16x32_bf16(a1, bZ, aZ[1][p], 0, 0, 0);
                if (kt < 8) {
                    aI[0][p] = __builtin_amdgcn_mfma_f32_16x16x32_bf16(a0, bN, aI[0][p], 0, 0, 0);
                    aI[1][p] = __builtin_amdgcn_mfma_f32_16x16x32_bf16(a1, bN, aI[1][p], 0, 0, 0);
                } else {
                    aH[0][p] = __builtin_amdgcn_mfma_f32_16x16x32_bf16(a0, bN, aH[0][p], 0, 0, 0);
                    aH[1][p] = __builtin_amdgcn_mfma_f32_16x16x32_bf16(a1, bN, aH[1][p], 0, 0, 0);
                }
            }
            __syncthreads();
        }

#pragma unroll
        for (int rf = 0; rf < 2; ++rf)
#pragma unroll
            for (int p = 0; p < 4; ++p) {
                int d = (wc * 4 + p) * 16 + l15;
#pragma unroll
                for (int r = 0; r < 4; ++r) {
                    int m = m0 + wr * 32 + rf * 16 + l4 * 4 + r;
                    float hv = hidden[(size_t)m * 128 + d];
                    float rg = sigm(aR[rf][p][r] + br[p]);
                    float zg = sigm(aZ[rf][p][r] + bz[p]);
                    float ng = fast_tanh(aI[rf][p][r] + bi[p] + rg * (aH[rf][p][r] + bh_[p]));
                    out[(size_t)m * 128 + d] = (1.f - zg) * hv + zg * ng;
                }
            }
    }
}

// ---------------------------------------------------------------------------
extern "C" void kernel_launch(void* const* d_in, const int* in_sizes, int n_in,
                              void* d_out, int out_size, void* d_ws, size_t ws_size,
                              hipStream_t stream) {
    const float* A     = (const float*)d_in[0];
    const float* hidden= (const float*)d_in[1];
    const float* mi    = (const float*)d_in[2];
    const float* xa    = (const float*)d_in[3];
    const int*   len   = (const int*)  d_in[4];
    const float* gwih  = (const float*)d_in[5];
    const float* gwhh  = (const float*)d_in[6];
    const float* gbih  = (const float*)d_in[7];
    const float* gbhh  = (const float*)d_in[8];
    const float* wih   = (const float*)d_in[9];
    const float* whh   = (const float*)d_in[10];
    const float* bih   = (const float*)d_in[11];
    const float* bhh   = (const float*)d_in[12];
    const float* biah  = (const float*)d_in[13];
    const float* bioh  = (const float*)d_in[14];
    const float* w_in  = (const float*)d_in[15];
    const float* b_in  = (const float*)d_in[16];
    const float* w_out = (const float*)d_in[17];
    const float* b_out = (const float*)d_in[18];

    float* out = (float*)d_out;
    // ws layout (8.5 MB):
    //   [0, 8.39 MB):      mh bf16 [M][128]   (k1 -> k23)
    //   [8.39 MB, +128KB): perm int [M]       (k0 -> k1)
    short* mh   = (short*)d_ws;
    int*   perm = (int*)((char*)d_ws + (size_t)M_ * D_ * 2);

    k0_sort    <<<1,      1024, 0, stream>>>(len, perm);
    k1_gru_mfma<<<256,     512, 0, stream>>>(xa, len, perm, gwih, gwhh, gbih, gbhh, mh);
    k23_fused  <<<B_,      512, 0, stream>>>(A, hidden, mi, mh,
                                             w_in, b_in, w_out, b_out,
                                             biah, bioh, wih, whh, bih, bhh, out);
}